// Round 3
// baseline (238.128 us; speedup 1.0000x reference)
//
#include <hip/hip_runtime.h>
#include <math.h>

#define D_MODEL 4096
#define NEXP    64
#define NTOK    16384
#define BT      32                 // tokens per block
#define NSTEP   64                 // K-steps of 64
#define LGSTR   72                 // logits LDS stride (pad)

typedef __attribute__((ext_vector_type(8))) short  bf16x8;
typedef __attribute__((ext_vector_type(4))) float  f32x4;

__device__ __forceinline__ unsigned cvt_pk_bf16(float lo, float hi) {
    unsigned r;
    asm("v_cvt_pk_bf16_f32 %0, %1, %2" : "=v"(r) : "v"(lo), "v"(hi));
    return r;
}
__device__ __forceinline__ float u2f(unsigned u) {
    union { unsigned u; float f; } v; v.u = u; return v.f;
}
__device__ __forceinline__ unsigned short f2bf_rn(float f) {
    union { float f; unsigned u; } v; v.f = f;
    unsigned r = v.u + 0x7fffu + ((v.u >> 16) & 1u);
    return (unsigned short)(r >> 16);
}
__device__ __forceinline__ float bf2f(unsigned short h) {
    union { unsigned u; float f; } v; v.u = ((unsigned)h) << 16;
    return v.f;
}

// (v,i) pair merge keeping jax.lax.top_k semantics (lower index wins ties)
__device__ __forceinline__ void top2_merge(float& v1, int& i1, float& v2, int& i2,
                                           float ov1, int oi1, float ov2, int oi2) {
    if (ov1 > v1 || (ov1 == v1 && oi1 < i1)) {
        float nv2 = v1; int ni2 = i1;
        if (ov2 > nv2 || (ov2 == nv2 && oi2 < ni2)) { nv2 = ov2; ni2 = oi2; }
        v1 = ov1; i1 = oi1; v2 = nv2; i2 = ni2;
    } else {
        if (ov1 > v2 || (ov1 == v2 && oi1 < i2)) { v2 = ov1; i2 = oi1; }
    }
}

// ---------------------------------------------------------------------------
// k0: split W into bf16 hi/lo halves in ws; block 0 also zeros expert_counts.
// ---------------------------------------------------------------------------
__global__ __launch_bounds__(256)
void k0_split_w(const float* __restrict__ W, unsigned short* __restrict__ ws,
                float* __restrict__ out) {
    if (blockIdx.x == 0 && threadIdx.x < NEXP)
        out[(size_t)2 * NTOK * NEXP + threadIdx.x] = 0.f;
    int i = (blockIdx.x * 256 + threadIdx.x) * 4;
    float4 v = *reinterpret_cast<const float4*>(&W[i]);
    unsigned short h[4], l[4];
    float f[4] = {v.x, v.y, v.z, v.w};
#pragma unroll
    for (int k = 0; k < 4; ++k) {
        h[k] = f2bf_rn(f[k]);
        l[k] = f2bf_rn(f[k] - bf2f(h[k]));
    }
    *reinterpret_cast<short4*>(&ws[i])                  = make_short4(h[0], h[1], h[2], h[3]);
    *reinterpret_cast<short4*>(&ws[NEXP * D_MODEL + i]) = make_short4(l[0], l[1], l[2], l[3]);
}

// ---------------------------------------------------------------------------
// k1: barrier-free fused router. 8 waves: wave w -> token tile (w>>2),
// expert strip (w&3). A loaded register-direct from global (L1/L2 absorbs
// the 4x strip redundancy); A split to bf16 hi/lo via v_cvt_pk_bf16_f32.
// ---------------------------------------------------------------------------
__global__ __launch_bounds__(512, 4)
void k1_fused(const float* __restrict__ x, const unsigned short* __restrict__ wsplit,
              const float* __restrict__ bias, float* __restrict__ out) {
    __shared__ __align__(16) float lg[BT * LGSTR];   // 9216 B
    __shared__ float cnt[NEXP];

    const int tid  = threadIdx.x;
    const int t0   = blockIdx.x * BT;
    const int w    = tid >> 6;
    const int lane = tid & 63;
    const int m    = w >> 2;            // token tile (0/1)
    const int n    = w & 3;             // expert strip
    const int rowl = lane & 15;
    const int grp  = lane >> 4;         // 0..3 (K-slot)

    if (tid < NEXP) cnt[tid] = 0.f;

    const float* ap = x + (size_t)(t0 + m * 16 + rowl) * D_MODEL + grp * 8;
    const int e = n * 16 + rowl;
    const unsigned short* bhp = wsplit + (size_t)e * D_MODEL + grp * 8;
    const unsigned short* blp = bhp + (size_t)NEXP * D_MODEL;

    f32x4 acc = {0.f, 0.f, 0.f, 0.f};

    for (int t = 0; t < NSTEP; ++t) {
#pragma unroll
        for (int f = 0; f < 2; ++f) {
            const int ko = t * 64 + f * 32;           // f32/bf16 element offset
            f32x4 c0 = *reinterpret_cast<const f32x4*>(ap + ko);
            f32x4 c1 = *reinterpret_cast<const f32x4*>(ap + ko + 4);
            float a[8] = {c0.x, c0.y, c0.z, c0.w, c1.x, c1.y, c1.z, c1.w};
            union { bf16x8 v; unsigned u[4]; } ah, al;
#pragma unroll
            for (int p = 0; p < 4; ++p) {
                unsigned h = cvt_pk_bf16(a[2 * p], a[2 * p + 1]);
                float r0 = a[2 * p]     - u2f(h << 16);
                float r1 = a[2 * p + 1] - u2f(h & 0xffff0000u);
                ah.u[p] = h;
                al.u[p] = cvt_pk_bf16(r0, r1);
            }
            bf16x8 bh = *reinterpret_cast<const bf16x8*>(bhp + ko);
            bf16x8 bl = *reinterpret_cast<const bf16x8*>(blp + ko);
            acc = __builtin_amdgcn_mfma_f32_16x16x32_bf16(ah.v, bh, acc, 0, 0, 0);
            acc = __builtin_amdgcn_mfma_f32_16x16x32_bf16(ah.v, bl, acc, 0, 0, 0);
            acc = __builtin_amdgcn_mfma_f32_16x16x32_bf16(al.v, bh, acc, 0, 0, 0);
        }
    }

    // ---- epilogue: logits tile -> LDS, fused softmax + top2 (verified r2) ----
#pragma unroll
    for (int i = 0; i < 4; ++i)
        lg[(m * 16 + grp * 4 + i) * LGSTR + n * 16 + rowl] = acc[i];
    __syncthreads();

    const int token = tid >> 4;           // 0..31
    const int j     = tid & 15;           // 16 threads per token
    float4 v4 = *reinterpret_cast<const float4*>(&lg[token * LGSTR + j * 4]);
    float lv[4] = {v4.x + bias[j * 4 + 0], v4.y + bias[j * 4 + 1],
                   v4.z + bias[j * 4 + 2], v4.w + bias[j * 4 + 3]};

    float v1 = lv[0], v2 = -INFINITY;
    int   i1 = j * 4, i2 = 1 << 30;
#pragma unroll
    for (int k = 1; k < 4; ++k) {
        if (lv[k] > v1)      { v2 = v1; i2 = i1; v1 = lv[k]; i1 = j * 4 + k; }
        else if (lv[k] > v2) { v2 = lv[k]; i2 = j * 4 + k; }
    }
#pragma unroll
    for (int mask = 1; mask < 16; mask <<= 1) {
        float ov1 = __shfl_xor(v1, mask);
        int   oi1 = __shfl_xor(i1, mask);
        float ov2 = __shfl_xor(v2, mask);
        int   oi2 = __shfl_xor(i2, mask);
        top2_merge(v1, i1, v2, i2, ov1, oi1, ov2, oi2);
    }
    float s = 0.f;
#pragma unroll
    for (int k = 0; k < 4; ++k) s += __expf(lv[k] - v1);
#pragma unroll
    for (int mask = 1; mask < 16; mask <<= 1) s += __shfl_xor(s, mask);

    const float invS = 1.f / s;
    const float s1 = invS;
    const float s2 = __expf(v2 - v1) * invS;

    const int tg = t0 + token;
    float4 o = make_float4(0.f, 0.f, 0.f, 0.f);
    if ((i1 >> 2) == j) (&o.x)[i1 & 3] = s1;
    if ((i2 >> 2) == j) (&o.x)[i2 & 3] = s2;
    *reinterpret_cast<float4*>(&out[(size_t)tg * NEXP + j * 4]) = o;
    *reinterpret_cast<float4*>(&out[(size_t)NTOK * NEXP + (size_t)tg * NEXP + j * 4]) = o;

    if (j == 0) {
        atomicAdd(&cnt[i1], s1);
        atomicAdd(&cnt[i2], s2);
    }
    __syncthreads();
    if (tid < NEXP)
        atomicAdd(&out[(size_t)2 * NTOK * NEXP + tid], cnt[tid]);
}

// ---------------------------------------------------------------------------
extern "C" void kernel_launch(void* const* d_in, const int* in_sizes, int n_in,
                              void* d_out, int out_size, void* d_ws, size_t ws_size,
                              hipStream_t stream) {
    const float* x = (const float*)d_in[0];
    const float* W = (const float*)d_in[1];
    const float* b = (const float*)d_in[2];
    float* out = (float*)d_out;
    unsigned short* ws = (unsigned short*)d_ws;   // 1 MiB

    k0_split_w<<<NEXP * D_MODEL / (256 * 4), 256, 0, stream>>>(W, ws, out);
    k1_fused<<<NTOK / BT, 512, 0, stream>>>(x, ws, b, out);
}

// Round 4
// 141.419 us; speedup vs baseline: 1.6839x; 1.6839x over previous
//
#include <hip/hip_runtime.h>
#include <math.h>

#define D_MODEL 4096
#define NEXP    64
#define NTOK    16384
#define BT      32                 // tokens per block
#define NSTEP   64                 // K-steps of 64
#define LGSTR   72                 // logits LDS stride (pad)

typedef __attribute__((ext_vector_type(8))) short  bf16x8;
typedef __attribute__((ext_vector_type(4))) float  f32x4;

__device__ __forceinline__ unsigned short f2bf_rn(float f) {
    union { float f; unsigned u; } v; v.f = f;
    unsigned r = v.u + 0x7fffu + ((v.u >> 16) & 1u);
    return (unsigned short)(r >> 16);
}
__device__ __forceinline__ float bf2f(unsigned short h) {
    union { unsigned u; float f; } v; v.u = ((unsigned)h) << 16;
    return v.f;
}
// split two floats into packed bf16 hi-word and lo-word (RNE both)
__device__ __forceinline__ void split2(float f0, float f1, unsigned& hw, unsigned& lw) {
    unsigned short h0 = f2bf_rn(f0), h1 = f2bf_rn(f1);
    unsigned short l0 = f2bf_rn(f0 - bf2f(h0)), l1 = f2bf_rn(f1 - bf2f(h1));
    hw = (unsigned)h0 | ((unsigned)h1 << 16);
    lw = (unsigned)l0 | ((unsigned)l1 << 16);
}

// (v,i) pair merge keeping jax.lax.top_k semantics (lower index wins ties)
__device__ __forceinline__ void top2_merge(float& v1, int& i1, float& v2, int& i2,
                                           float ov1, int oi1, float ov2, int oi2) {
    if (ov1 > v1 || (ov1 == v1 && oi1 < i1)) {
        float nv2 = v1; int ni2 = i1;
        if (ov2 > nv2 || (ov2 == nv2 && oi2 < ni2)) { nv2 = ov2; ni2 = oi2; }
        v1 = ov1; i1 = oi1; v2 = nv2; i2 = ni2;
    } else {
        if (ov1 > v2 || (ov1 == v2 && oi1 < i2)) { v2 = ov1; i2 = oi1; }
    }
}

// ---------------------------------------------------------------------------
// k0: split W into bf16 hi/lo halves in ws; block 0 also zeros expert_counts.
// ---------------------------------------------------------------------------
__global__ __launch_bounds__(256)
void k0_split_w(const float* __restrict__ W, unsigned short* __restrict__ ws,
                float* __restrict__ out) {
    if (blockIdx.x == 0 && threadIdx.x < NEXP)
        out[(size_t)2 * NTOK * NEXP + threadIdx.x] = 0.f;
    int i = (blockIdx.x * 256 + threadIdx.x) * 4;
    float4 v = *reinterpret_cast<const float4*>(&W[i]);
    unsigned short h[4], l[4];
    float f[4] = {v.x, v.y, v.z, v.w};
#pragma unroll
    for (int k = 0; k < 4; ++k) {
        h[k] = f2bf_rn(f[k]);
        l[k] = f2bf_rn(f[k] - bf2f(h[k]));
    }
    *reinterpret_cast<short4*>(&ws[i])                  = make_short4(h[0], h[1], h[2], h[3]);
    *reinterpret_cast<short4*>(&ws[NEXP * D_MODEL + i]) = make_short4(l[0], l[1], l[2], l[3]);
}

// ---------------------------------------------------------------------------
// k1: fused router. x staged into LDS as PRE-SPLIT bf16 hi/lo tiles
// (conversion once per tile, not 4x); inner loop is ds_read_b128 -> MFMA.
// 8 waves: wave w -> token tile (w>>2), expert strip (w&3). One barrier/step.
// ---------------------------------------------------------------------------
__global__ __launch_bounds__(512, 4)
void k1_fused(const float* __restrict__ x, const unsigned short* __restrict__ wsplit,
              const float* __restrict__ bias, float* __restrict__ out) {
    __shared__ unsigned xh[2][BT * 32];   // 2 x 4 KiB  (32 uints = 64 bf16 per row)
    __shared__ unsigned xl[2][BT * 32];   // 2 x 4 KiB
    __shared__ float lg[BT * LGSTR];      // 9216 B
    __shared__ float cnt[NEXP];

    const int tid  = threadIdx.x;
    const int t0   = blockIdx.x * BT;
    const int w    = tid >> 6;
    const int lane = tid & 63;
    const int m    = w >> 2;            // token tile (0/1)
    const int n    = w & 3;             // expert strip
    const int rowl = lane & 15;
    const int grp  = lane >> 4;         // 0..3 (K-slot)

    if (tid < NEXP) cnt[tid] = 0.f;

    // staging geometry: thread -> (row, 8B-subchunk), XOR-swizzled chunk
    const int s_row = tid >> 4;
    const int s_s   = tid & 15;
    const int s_off = s_row * 32 + (((s_s >> 1) ^ (s_row & 7)) << 2) + ((s_s & 1) << 1);
    const float* gsrc = x + (size_t)(t0 + s_row) * D_MODEL + s_s * 4;

    // A-fragment geometry (same swizzle on read, 16B chunks)
    const int a_row  = m * 16 + rowl;
    const int a_sw   = a_row & 7;
    const int a_base = a_row * 32;
    const int c0off  = a_base + ((grp ^ a_sw) << 2);
    const int c1off  = a_base + (((4 + grp) ^ a_sw) << 2);

    // B pointers (bf16 hi/lo W, L2-resident)
    const int e = n * 16 + rowl;
    const unsigned short* bhp = wsplit + (size_t)e * D_MODEL + grp * 8;
    const unsigned short* blp = bhp + (size_t)NEXP * D_MODEL;

    f32x4 acc = {0.f, 0.f, 0.f, 0.f};

#define LOADX(t) (*reinterpret_cast<const float4*>(gsrc + (t) * 64))
#define LOADB(t, bh0, bl0, bh1, bl1) do {                                 \
    bh0 = *reinterpret_cast<const bf16x8*>(bhp + (t) * 64);               \
    bh1 = *reinterpret_cast<const bf16x8*>(bhp + (t) * 64 + 32);          \
    bl0 = *reinterpret_cast<const bf16x8*>(blp + (t) * 64);               \
    bl1 = *reinterpret_cast<const bf16x8*>(blp + (t) * 64 + 32);          \
} while (0)
#define STAGE(v, b) do {                                                  \
    unsigned hw0, lw0, hw1, lw1;                                          \
    split2((v).x, (v).y, hw0, lw0);                                       \
    split2((v).z, (v).w, hw1, lw1);                                       \
    *reinterpret_cast<uint2*>(&xh[b][s_off]) = make_uint2(hw0, hw1);      \
    *reinterpret_cast<uint2*>(&xl[b][s_off]) = make_uint2(lw0, lw1);      \
} while (0)
#define COMPUTE(b, bh0, bl0, bh1, bl1) do {                               \
    bf16x8 ah0 = *reinterpret_cast<const bf16x8*>(&xh[b][c0off]);         \
    bf16x8 al0 = *reinterpret_cast<const bf16x8*>(&xl[b][c0off]);         \
    bf16x8 ah1 = *reinterpret_cast<const bf16x8*>(&xh[b][c1off]);         \
    bf16x8 al1 = *reinterpret_cast<const bf16x8*>(&xl[b][c1off]);         \
    acc = __builtin_amdgcn_mfma_f32_16x16x32_bf16(ah0, bh0, acc, 0, 0, 0); \
    acc = __builtin_amdgcn_mfma_f32_16x16x32_bf16(ah0, bl0, acc, 0, 0, 0); \
    acc = __builtin_amdgcn_mfma_f32_16x16x32_bf16(al0, bh0, acc, 0, 0, 0); \
    acc = __builtin_amdgcn_mfma_f32_16x16x32_bf16(ah1, bh1, acc, 0, 0, 0); \
    acc = __builtin_amdgcn_mfma_f32_16x16x32_bf16(ah1, bl1, acc, 0, 0, 0); \
    acc = __builtin_amdgcn_mfma_f32_16x16x32_bf16(al1, bh1, acc, 0, 0, 0); \
} while (0)

    // prologue: prefetch x(0),x(1), B(0),B(1); stage step 0
    float4 rA = LOADX(0);
    float4 rB = LOADX(1);
    bf16x8 bhE0, blE0, bhE1, blE1, bhO0, blO0, bhO1, blO1;
    LOADB(0, bhE0, blE0, bhE1, blE1);
    LOADB(1, bhO0, blO0, bhO1, blO1);
    STAGE(rA, 0);

    for (int t = 0; t < NSTEP; t += 2) {
        if (t + 2 < NSTEP) rA = LOADX(t + 2);
        __syncthreads();                          // buf0 (step t) visible
        COMPUTE(0, bhE0, blE0, bhE1, blE1);
        if (t + 2 < NSTEP) LOADB(t + 2, bhE0, blE0, bhE1, blE1);
        STAGE(rB, 1);                             // step t+1 into buf1
        if (t + 3 < NSTEP) rB = LOADX(t + 3);
        __syncthreads();                          // buf1 visible; buf0 free
        COMPUTE(1, bhO0, blO0, bhO1, blO1);
        if (t + 3 < NSTEP) LOADB(t + 3, bhO0, blO0, bhO1, blO1);
        if (t + 2 < NSTEP) STAGE(rA, 0);          // step t+2 into buf0
    }

    // ---- epilogue: logits tile -> LDS, fused softmax + top2 (verified) ----
#pragma unroll
    for (int i = 0; i < 4; ++i)
        lg[(m * 16 + grp * 4 + i) * LGSTR + n * 16 + rowl] = acc[i];
    __syncthreads();

    const int token = tid >> 4;           // 0..31
    const int j     = tid & 15;           // 16 threads per token
    float4 v4 = *reinterpret_cast<const float4*>(&lg[token * LGSTR + j * 4]);
    float lv[4] = {v4.x + bias[j * 4 + 0], v4.y + bias[j * 4 + 1],
                   v4.z + bias[j * 4 + 2], v4.w + bias[j * 4 + 3]};

    float v1 = lv[0], v2 = -INFINITY;
    int   i1 = j * 4, i2 = 1 << 30;
#pragma unroll
    for (int k = 1; k < 4; ++k) {
        if (lv[k] > v1)      { v2 = v1; i2 = i1; v1 = lv[k]; i1 = j * 4 + k; }
        else if (lv[k] > v2) { v2 = lv[k]; i2 = j * 4 + k; }
    }
#pragma unroll
    for (int mask = 1; mask < 16; mask <<= 1) {
        float ov1 = __shfl_xor(v1, mask);
        int   oi1 = __shfl_xor(i1, mask);
        float ov2 = __shfl_xor(v2, mask);
        int   oi2 = __shfl_xor(i2, mask);
        top2_merge(v1, i1, v2, i2, ov1, oi1, ov2, oi2);
    }
    float s = 0.f;
#pragma unroll
    for (int k = 0; k < 4; ++k) s += __expf(lv[k] - v1);
#pragma unroll
    for (int mask = 1; mask < 16; mask <<= 1) s += __shfl_xor(s, mask);

    const float invS = 1.f / s;
    const float s1 = invS;
    const float s2 = __expf(v2 - v1) * invS;

    const int tg = t0 + token;
    float4 o = make_float4(0.f, 0.f, 0.f, 0.f);
    if ((i1 >> 2) == j) (&o.x)[i1 & 3] = s1;
    if ((i2 >> 2) == j) (&o.x)[i2 & 3] = s2;
    *reinterpret_cast<float4*>(&out[(size_t)tg * NEXP + j * 4]) = o;
    *reinterpret_cast<float4*>(&out[(size_t)NTOK * NEXP + (size_t)tg * NEXP + j * 4]) = o;

    if (j == 0) {
        atomicAdd(&cnt[i1], s1);
        atomicAdd(&cnt[i2], s2);
    }
    __syncthreads();
    if (tid < NEXP)
        atomicAdd(&out[(size_t)2 * NTOK * NEXP + tid], cnt[tid]);
}

// ---------------------------------------------------------------------------
extern "C" void kernel_launch(void* const* d_in, const int* in_sizes, int n_in,
                              void* d_out, int out_size, void* d_ws, size_t ws_size,
                              hipStream_t stream) {
    const float* x = (const float*)d_in[0];
    const float* W = (const float*)d_in[1];
    const float* b = (const float*)d_in[2];
    float* out = (float*)d_out;
    unsigned short* ws = (unsigned short*)d_ws;   // 1 MiB

    k0_split_w<<<NEXP * D_MODEL / (256 * 4), 256, 0, stream>>>(W, ws, out);
    k1_fused<<<NTOK / BT, 512, 0, stream>>>(x, ws, b, out);
}